// Round 23
// baseline (122.169 us; speedup 1.0000x reference)
//
#include <hip/hip_runtime.h>
#include <hip/hip_bf16.h>
#include <stdint.h>

// DenseConv2d: input (32,128,56,56) f32, weight (256,128,3,3) f32, bias (256) f32
// stride 1, pad 1 -> out (32,256,56,56) f32.
// Round 23: TLP-max. BK=32 tiles (36 steps), 3x24KB LDS buffers (72KB) ->
// TWO 1024-thread blocks per CU = 8 waves/SIMD (launch_bounds(1024,8),
// VGPR budget 64). Single fragment bank (serial read->MFMA per tile; 8-wave
// TLP covers it -- the proven r20 mechanism, doubled). Depth-2 gload
// prefetch, per-wave-class counted vmcnt (2 or 1, never 0 till tail),
// ONE barrier/tile, chunked conflict-free LDS, fused prepass.

typedef __attribute__((ext_vector_type(8))) short bf16x8;
typedef __attribute__((ext_vector_type(8))) unsigned short ushort8;
typedef __attribute__((ext_vector_type(4))) float f32x4;

#define HW       56
#define SPATIAL  3136
#define C_IN     128
#define K_OUT    256
#define GEMM_K   1152
#define GEMM_N   100352      // 32*3136

#define PHW      58
#define PIMG     3364        // 58*58
#define PADTOT_AL 107656     // 32*3364 + 8 slack positions

#define BM       256
#define BN       128
#define NT32     36          // K-steps of 32 (tap = t>>2, cc = t&3)
#define BUFH     12288       // halves per LDS buffer: A 8192 + B 4096 (24 KiB)

__device__ __forceinline__ unsigned short f2bf(float f) {
    union { float f; unsigned int u; } v; v.f = f;
    unsigned int u = v.u + 0x7FFFu + ((v.u >> 16) & 1u);   // RTNE
    return (unsigned short)(u >> 16);
}

__device__ __forceinline__ void gload16(const unsigned short* g, unsigned short* l) {
    __builtin_amdgcn_global_load_lds(
        (const __attribute__((address_space(1))) unsigned int*)(g),
        (__attribute__((address_space(3))) unsigned int*)(l),
        16, 0, 0);
}

// single fused prepass:
//   blocks 0..1151    : weight -> w3 fragment chunks
//   blocks 1152..1265 : pad border zero
//   blocks 1266..3057 : input f32 NCHW -> pad bf16 padded-NHWC (interior)
__global__ __launch_bounds__(256)
void prep_all(const float* __restrict__ w, unsigned short* __restrict__ w3,
              const float* __restrict__ in, unsigned short* __restrict__ pad) {
    __shared__ __attribute__((aligned(16))) unsigned short l[56 * 136];
    const int b = blockIdx.x;
    const int tid = threadIdx.x;
    if (b < 1152) {
        int idx = b * 256 + tid;                 // 294912
        int rc   = idx / 18432;
        int rem  = idx % 18432;
        int tap  = rem / 2048;
        int rem2 = rem % 2048;
        int cc   = rem2 / 512;
        int s    = rem2 % 512;
        int li   = s >> 3, j = s & 7;
        int ko   = rc * 16 + (li & 15);
        int c    = cc * 32 + ((li >> 4) << 3) + j;
        w3[idx] = f2bf(w[(ko * C_IN + c) * 9 + tap]);
    } else if (b < 1266) {
        int idx = (b - 1152) * 256 + tid;        // 4*32*228 = 29184
        if (idx >= 29184) return;
        int cc  = idx / 7296;
        int r   = idx % 7296;
        int img = r / 228;
        int p   = r % 228;
        int pos;
        if (p < 58)       pos = p;
        else if (p < 116) pos = 57 * PHW + (p - 58);
        else { int i = p - 116; pos = (1 + (i >> 1)) * PHW + (i & 1) * 57; }
        unsigned short* d = pad + (size_t)cc * PADTOT_AL * 32
                          + ((size_t)img * PIMG + pos) * 32;
        const ushort8 z = (ushort8){0,0,0,0,0,0,0,0};
        *reinterpret_cast<ushort8*>(d)      = z;
        *reinterpret_cast<ushort8*>(d + 8)  = z;
        *reinterpret_cast<ushort8*>(d + 16) = z;
        *reinterpret_cast<ushort8*>(d + 24) = z;
    } else {
        const int bx = b - 1266;                 // 0..1791 = 32*56
        const int n = bx / HW, h = bx % HW;
        const float* src = in + (size_t)n * C_IN * SPATIAL + h * HW;
        #pragma unroll
        for (int i = 0; i < 28; ++i) {           // 7168 = 28*256
            int idx = i * 256 + tid;
            int c = idx / HW, wv = idx % HW;
            l[wv * 136 + c] = f2bf(src[(size_t)c * SPATIAL + wv]);
        }
        __syncthreads();
        const int prow = n * PIMG + (h + 1) * PHW;
        #pragma unroll
        for (int j = 0; j < 4; ++j) {
            int chunk = j * 256 + tid;           // 896 = 56*16 chunks of 8 halves
            if (chunk < 896) {
                int wv = chunk >> 4, c8 = chunk & 15;
                int cc = c8 >> 2, sub = c8 & 3;
                unsigned short* dst = pad + (size_t)cc * PADTOT_AL * 32
                                    + (size_t)(prow + wv + 1) * 32 + sub * 8;
                *reinterpret_cast<ushort8*>(dst) =
                    *reinterpret_cast<const ushort8*>(&l[wv * 136 + c8 * 8]);
            }
        }
    }
}

// ---------------- main kernel: 8 waves/SIMD (2 blocks/CU) ----------------
// LDS buffer (halves): A chunks [rc*512] rc=0..15; B at 8192: [bc*512] bc=0..7.
// Chunk slot l = (row/col l&15, k-gran l>>4).
__global__ __launch_bounds__(1024, 8)
void conv_tlp8(const unsigned short* __restrict__ pad,   // [4][PADTOT_AL][32]
               const unsigned short* __restrict__ w3,    // chunked weights
               const float* __restrict__ bias,
               float* __restrict__ out) {
    __shared__ __attribute__((aligned(16))) unsigned short lds[3 * BUFH]; // 72 KiB

    const int tid  = threadIdx.x;
    const int wave = tid >> 6;          // 0..15
    const int lane = tid & 63;
    const int la   = lane & 15;
    const int lkh  = lane >> 4;

    // bijective XCD swizzle: 784 blocks = 8 * 98
    const int bid = blockIdx.x;
    const int nt  = (bid & 7) * 98 + (bid >> 3);      // 0..783
    const int g0  = nt * BN;

    const int wr = wave >> 2, wc = wave & 3;          // 4m x 4n, 64x32 tiles

    // ---- staging descriptors ----
    // A: wave stages rchunk rc = wave (1 gload/tile).
    const unsigned short* aw = w3 + (size_t)wave * 18432 + lane * 8;
    // B: waves 0..7 stage col-chunk bc = wave (1 gload/tile).
    const unsigned short* bsrc;
    {
        int col = g0 + (wave & 7) * 16 + la;
        int img = col / SPATIAL;
        int pos = col - img * SPATIAL;
        int oh  = pos / HW, ow = pos - oh * HW;
        bsrc = pad + (size_t)(img * PIMG + (oh + 1) * PHW + (ow + 1)) * 32 + lkh * 8;
    }
    const bool stagesB = (wave < 8);

    f32x4 acc[4][2];
    #pragma unroll
    for (int i = 0; i < 4; ++i)
        #pragma unroll
        for (int j = 0; j < 2; ++j)
            acc[i][j] = (f32x4){0.f, 0.f, 0.f, 0.f};

    // stage step tn (tap = tn>>2, cc = tn&3) into buf[tn%3]
    auto STAGE = [&](int tn) {
        const int tap = tn >> 2, cc = tn & 3;
        const int dr = tap / 3 - 1, dsx = tap % 3 - 1;
        unsigned short* dst = &lds[(tn % 3) * BUFH];
        gload16(aw + (size_t)(tap * 4 + cc) * 512, dst + wave * 512);
        if (stagesB)
            gload16(bsrc + (size_t)cc * (PADTOT_AL * 32) + (dr * PHW + dsx) * 32,
                    dst + 8192 + wave * 512);
    };

    // single fragment bank (reads for t+1 issued AFTER MFMA(t) retires frags)
    bf16x8 a[4], b[2];

    auto READF = [&](int tn) {
        const unsigned short* Ab = &lds[(tn % 3) * BUFH];
        #pragma unroll
        for (int mi = 0; mi < 4; ++mi)
            a[mi] = *reinterpret_cast<const bf16x8*>(
                &Ab[(wr * 4 + mi) * 512 + lane * 8]);
        #pragma unroll
        for (int nj = 0; nj < 2; ++nj)
            b[nj] = *reinterpret_cast<const bf16x8*>(
                &Ab[8192 + (wc * 2 + nj) * 512 + lane * 8]);
    };

    // prologue: steps 0 and 1 staged; wait step-0 (step-1 stays in flight)
    STAGE(0); STAGE(1);
    if (stagesB) asm volatile("s_waitcnt vmcnt(2)" ::: "memory");
    else         asm volatile("s_waitcnt vmcnt(1)" ::: "memory");
    __builtin_amdgcn_s_barrier();
    asm volatile("" ::: "memory");
    READF(0);                          // 6 ds_read in flight into the loop

    #pragma unroll
    for (int t = 0; t < NT32; ++t) {
        if (t + 2 < NT32) STAGE(t + 2);               // buf (t+2)%3

        asm volatile("s_waitcnt lgkmcnt(0)" ::: "memory");   // frags of t ready
        __builtin_amdgcn_sched_barrier(0);
        __builtin_amdgcn_s_setprio(1);
        #pragma unroll
        for (int mi = 0; mi < 4; ++mi)
            #pragma unroll
            for (int nj = 0; nj < 2; ++nj)
                acc[mi][nj] = __builtin_amdgcn_mfma_f32_16x16x32_bf16(
                    a[mi], b[nj], acc[mi][nj], 0, 0, 0);
        __builtin_amdgcn_s_setprio(0);

        if (t + 1 < NT32) {
            // wait: t+1's loads landed; t+2's stay in flight (counted)
            if (t + 2 < NT32) {
                if (stagesB) asm volatile("s_waitcnt vmcnt(2)" ::: "memory");
                else         asm volatile("s_waitcnt vmcnt(1)" ::: "memory");
            } else {
                asm volatile("s_waitcnt vmcnt(0)" ::: "memory");
            }
            __builtin_amdgcn_s_barrier();
            asm volatile("" ::: "memory");
            READF(t + 1);              // 6 ds_read, fly over loop backedge
        }
    }

    // ---- epilogue: D col = lane&15, row = (lane>>4)*4 + reg ----
    #pragma unroll
    for (int mi = 0; mi < 4; ++mi) {
        const int mb = wr * 64 + mi * 16 + lkh * 4;
        const f32x4 bv4 = *reinterpret_cast<const f32x4*>(&bias[mb]);
        #pragma unroll
        for (int nj = 0; nj < 2; ++nj) {
            const int gcol = g0 + wc * 32 + nj * 16;   // 16-aligned: one image
            const int n2 = gcol / SPATIAL;
            const int p2 = gcol - n2 * SPATIAL + la;
            float* op = out + ((size_t)(n2 * K_OUT + mb)) * SPATIAL + p2;
            op[0]                   = acc[mi][nj][0] + bv4[0];
            op[SPATIAL]             = acc[mi][nj][1] + bv4[1];
            op[2 * SPATIAL]         = acc[mi][nj][2] + bv4[2];
            op[3 * (size_t)SPATIAL] = acc[mi][nj][3] + bv4[3];
        }
    }
}

// ---------------- fallback (round-1 path) if ws is too small ----------------
#define LDK 40
__global__ __launch_bounds__(256)
void conv_mfma_fallback(const float* __restrict__ in,
                        const float* __restrict__ wraw,
                        const float* __restrict__ bias,
                        float* __restrict__ out) {
    __shared__ __attribute__((aligned(16))) unsigned short lA[128 * LDK];
    __shared__ __attribute__((aligned(16))) unsigned short lB[128 * LDK];
    const int tid = threadIdx.x;
    const int m0  = blockIdx.y * 128;
    const int g0  = blockIdx.x * 128;
    const int wave = tid >> 6, lane = tid & 63;
    const int wr = wave >> 1, wc = wave & 1;
    const int la = lane & 15, lkh = lane >> 4, lk = lkh * 8;

    f32x4 acc[4][4];
    #pragma unroll
    for (int i = 0; i < 4; ++i)
        #pragma unroll
        for (int j = 0; j < 4; ++j)
            acc[i][j] = (f32x4){0.f, 0.f, 0.f, 0.f};

    const int jj = tid & 127;
    const int kb = (tid >> 7) * 16;
    const int g = g0 + jj;
    const int nimg = g / SPATIAL;
    const int pos  = g % SPATIAL;
    const int oh = pos / HW, ow = pos % HW;

    for (int tap = 0; tap < 9; ++tap) {
        const int dr = tap / 3 - 1, dsx = tap % 3 - 1;
        const int ih = oh + dr, iw = ow + dsx;
        const bool valid = ((unsigned)ih < HW) && ((unsigned)iw < HW);
        const float* src = in + ((nimg * C_IN) * HW + ih) * HW + iw;
        for (int c0 = 0; c0 < C_IN; c0 += 32) {
            #pragma unroll
            for (int i = 0; i < 2; ++i) {
                const int ch = tid * 2 + i;
                const int row = ch >> 2;
                const int kp = (ch & 3) * 8;
                ushort8 v;
                #pragma unroll
                for (int e = 0; e < 8; ++e)
                    v[e] = f2bf(wraw[((m0 + row) * C_IN + c0 + kp + e) * 9 + tap]);
                *reinterpret_cast<ushort8*>(&lA[row * LDK + kp]) = v;
            }
            {
                ushort8 v0, v1;
                #pragma unroll
                for (int i = 0; i < 8; ++i)
                    v0[i] = f2bf(valid ? src[(c0 + kb + i) * SPATIAL] : 0.f);
                #pragma unroll
                for (int i = 0; i < 8; ++i)
                    v1[i] = f2bf(valid ? src[(c0 + kb + 8 + i) * SPATIAL] : 0.f);
                *reinterpret_cast<ushort8*>(&lB[jj * LDK + kb])     = v0;
                *reinterpret_cast<ushort8*>(&lB[jj * LDK + kb + 8]) = v1;
            }
            __syncthreads();
            bf16x8 af[4], bv[4];
            #pragma unroll
            for (int f = 0; f < 4; ++f) {
                af[f] = *reinterpret_cast<const bf16x8*>(&lA[(wr * 64 + f * 16 + la) * LDK + lk]);
                bv[f] = *reinterpret_cast<const bf16x8*>(&lB[(wc * 64 + f * 16 + la) * LDK + lk]);
            }
            #pragma unroll
            for (int fi = 0; fi < 4; ++fi)
                #pragma unroll
                for (int fj = 0; fj < 4; ++fj)
                    acc[fi][fj] = __builtin_amdgcn_mfma_f32_16x16x32_bf16(
                        af[fi], bv[fj], acc[fi][fj], 0, 0, 0);
            __syncthreads();
        }
    }
    const int mbase = m0 + wr * 64;
    const int cbase = g0 + wc * 64;
    #pragma unroll
    for (int fi = 0; fi < 4; ++fi) {
        float bvv[4];
        #pragma unroll
        for (int r = 0; r < 4; ++r)
            bvv[r] = bias[mbase + fi * 16 + lkh * 4 + r];
        #pragma unroll
        for (int fj = 0; fj < 4; ++fj) {
            const int gcol = cbase + fj * 16 + la;
            const int n2 = gcol / SPATIAL;
            const int p2 = gcol % SPATIAL;
            float* op = out + (size_t)(n2 * K_OUT) * SPATIAL + p2;
            #pragma unroll
            for (int r = 0; r < 4; ++r)
                op[(size_t)(mbase + fi * 16 + lkh * 4 + r) * SPATIAL] = acc[fi][fj][r] + bvv[r];
        }
    }
}

extern "C" void kernel_launch(void* const* d_in, const int* in_sizes, int n_in,
                              void* d_out, int out_size, void* d_ws, size_t ws_size,
                              hipStream_t stream) {
    const float* in   = (const float*)d_in[0];
    const float* w    = (const float*)d_in[1];
    const float* bias = (const float*)d_in[2];
    float* out = (float*)d_out;

    // ws layout (halves): pad [4*PADTOT_AL*32] | w3 [294912]
    const size_t pad_halves = 4ull * PADTOT_AL * 32ull;     // 13,779,968
    const size_t need_bytes = (pad_halves + 294912ull) * 2ull;  // ~28.15 MB

    if (ws_size >= need_bytes) {
        unsigned short* pad = (unsigned short*)d_ws;
        unsigned short* w3  = pad + pad_halves;
        prep_all<<<1266 + 32 * HW, 256, 0, stream>>>(w, w3, in, pad);
        conv_tlp8<<<GEMM_N / BN, 1024, 0, stream>>>(pad, w3, bias, out);
    } else {
        dim3 grid(GEMM_N / 128, K_OUT / 128);
        conv_mfma_fallback<<<grid, 256, 0, stream>>>(in, w, bias, out);
    }
}

// Round 24
// 92.027 us; speedup vs baseline: 1.3275x; 1.3275x over previous
//
#include <hip/hip_runtime.h>
#include <hip/hip_bf16.h>
#include <stdint.h>

// DenseConv2d: input (32,128,56,56) f32, weight (256,128,3,3) f32, bias (256) f32
// stride 1, pad 1 -> out (32,256,56,56) f32.
// FINAL (= round 22, best verified: 92.5us total):
// - single fused prepass launch: weight->w3 MFMA-fragment chunks + pad border
//   zero + input->padded-NHWC bf16 (~8us)
// - main conv_tlp (77us, MfmaUtil 31%, occupancy 32%, 0 bank conflicts):
//   implicit GEMM 256x128 block, 1024 threads = 16 waves (4 waves/SIMD -- the
//   proven TLP lever, r20: 88->75.6us), 64x32 wave tiles, K-tile 64,
//   3 rotating 48KB LDS buffers, depth-2 gload_lds prefetch, cross-phase
//   register-fragment double bank, ONE barrier per K-tile, counted
//   s_waitcnt vmcnt(3)/lgkmcnt(6) (never 0 until the tail), setprio,
//   chunked conflict-free LDS layout, bijective XCD swizzle.
// Closed cells (counter evidence): 2-phase loops ~100-130us; 2-wave/SIMD
// pipelines 85-105us; direct-to-register defeated by the register allocator
// (r13/14/16/17); 64x64@16-wave register-infeasible (r21); 8 waves/SIMD
// collapses the schedule (r23: VGPR 32, MfmaUtil 21, 111us).

typedef __attribute__((ext_vector_type(8))) short bf16x8;
typedef __attribute__((ext_vector_type(8))) unsigned short ushort8;
typedef __attribute__((ext_vector_type(4))) float f32x4;

#define HW       56
#define SPATIAL  3136
#define C_IN     128
#define K_OUT    256
#define GEMM_K   1152
#define GEMM_N   100352      // 32*3136

#define PHW      58
#define PIMG     3364        // 58*58
#define PADTOT_AL 107656     // 32*3364 + 8 slack positions

#define BM       256
#define BN       128
#define NTILE    18          // K-tiles of 64 (tap = t>>1, ch-half = t&1)
#define BUFH     24576       // halves per LDS buffer: A 16384 + B 8192 (48 KiB)

__device__ __forceinline__ unsigned short f2bf(float f) {
    union { float f; unsigned int u; } v; v.f = f;
    unsigned int u = v.u + 0x7FFFu + ((v.u >> 16) & 1u);   // RTNE
    return (unsigned short)(u >> 16);
}

__device__ __forceinline__ void gload16(const unsigned short* g, unsigned short* l) {
    __builtin_amdgcn_global_load_lds(
        (const __attribute__((address_space(1))) unsigned int*)(g),
        (__attribute__((address_space(3))) unsigned int*)(l),
        16, 0, 0);
}

// single fused prepass:
//   blocks 0..1151    : weight -> w3 fragment chunks
//   blocks 1152..1265 : pad border zero
//   blocks 1266..3057 : input f32 NCHW -> pad bf16 padded-NHWC (interior)
// All three write disjoint regions; order-independent.
__global__ __launch_bounds__(256)
void prep_all(const float* __restrict__ w, unsigned short* __restrict__ w3,
              const float* __restrict__ in, unsigned short* __restrict__ pad) {
    __shared__ __attribute__((aligned(16))) unsigned short l[56 * 136];
    const int b = blockIdx.x;
    const int tid = threadIdx.x;
    if (b < 1152) {
        int idx = b * 256 + tid;                 // 294912
        int rc   = idx / 18432;
        int rem  = idx % 18432;
        int tap  = rem / 2048;
        int rem2 = rem % 2048;
        int cc   = rem2 / 512;
        int s    = rem2 % 512;
        int li   = s >> 3, j = s & 7;
        int ko   = rc * 16 + (li & 15);
        int c    = cc * 32 + ((li >> 4) << 3) + j;
        w3[idx] = f2bf(w[(ko * C_IN + c) * 9 + tap]);
    } else if (b < 1266) {
        int idx = (b - 1152) * 256 + tid;        // 4*32*228 = 29184
        if (idx >= 29184) return;
        int cc  = idx / 7296;
        int r   = idx % 7296;
        int img = r / 228;
        int p   = r % 228;
        int pos;
        if (p < 58)       pos = p;
        else if (p < 116) pos = 57 * PHW + (p - 58);
        else { int i = p - 116; pos = (1 + (i >> 1)) * PHW + (i & 1) * 57; }
        unsigned short* d = pad + (size_t)cc * PADTOT_AL * 32
                          + ((size_t)img * PIMG + pos) * 32;
        const ushort8 z = (ushort8){0,0,0,0,0,0,0,0};
        *reinterpret_cast<ushort8*>(d)      = z;
        *reinterpret_cast<ushort8*>(d + 8)  = z;
        *reinterpret_cast<ushort8*>(d + 16) = z;
        *reinterpret_cast<ushort8*>(d + 24) = z;
    } else {
        const int bx = b - 1266;                 // 0..1791 = 32*56
        const int n = bx / HW, h = bx % HW;
        const float* src = in + (size_t)n * C_IN * SPATIAL + h * HW;
        #pragma unroll
        for (int i = 0; i < 28; ++i) {           // 7168 = 28*256
            int idx = i * 256 + tid;
            int c = idx / HW, wv = idx % HW;
            l[wv * 136 + c] = f2bf(src[(size_t)c * SPATIAL + wv]);
        }
        __syncthreads();
        const int prow = n * PIMG + (h + 1) * PHW;
        #pragma unroll
        for (int j = 0; j < 4; ++j) {
            int chunk = j * 256 + tid;           // 896 = 56*16 chunks of 8 halves
            if (chunk < 896) {
                int wv = chunk >> 4, c8 = chunk & 15;
                int cc = c8 >> 2, sub = c8 & 3;
                unsigned short* dst = pad + (size_t)cc * PADTOT_AL * 32
                                    + (size_t)(prow + wv + 1) * 32 + sub * 8;
                *reinterpret_cast<ushort8*>(dst) =
                    *reinterpret_cast<const ushort8*>(&l[wv * 136 + c8 * 8]);
            }
        }
    }
}

// ---------------- main kernel: 16-wave TLP pipeline (r20/r22, 77us) ----------------
// LDS buffer layout (halves): A chunks [(rc*2+kc)*512] rc=0..15, then at 16384
// B chunks [(bc*2+kc)*512] bc=0..7. Chunk slot l = (row/col l&15, k-gran l>>4).
__global__ __launch_bounds__(1024, 1)
void conv_tlp(const unsigned short* __restrict__ pad,   // [4][PADTOT_AL][32]
              const unsigned short* __restrict__ w3,    // chunked weights
              const float* __restrict__ bias,
              float* __restrict__ out) {
    __shared__ __attribute__((aligned(16))) unsigned short lds[3 * BUFH]; // 144 KiB

    const int tid  = threadIdx.x;
    const int wave = tid >> 6;          // 0..15
    const int lane = tid & 63;
    const int la   = lane & 15;
    const int lkh  = lane >> 4;

    // bijective XCD swizzle: 784 blocks = 8 * 98
    const int bid = blockIdx.x;
    const int nt  = (bid & 7) * 98 + (bid >> 3);      // 0..783
    const int g0  = nt * BN;

    const int wr = wave >> 2, wc = wave & 3;          // 4m x 4n, 64x32 tiles

    // ---- staging descriptors (wave-uniform: 3 gloads per wave per tile) ----
    const unsigned short* aw = w3 + (size_t)wave * 18432 + lane * 8;
    const unsigned short* bsrc;
    {
        int col = g0 + (wave >> 1) * 16 + la;
        int img = col / SPATIAL;
        int pos = col - img * SPATIAL;
        int oh  = pos / HW, ow = pos - oh * HW;
        bsrc = pad + (size_t)(img * PIMG + (oh + 1) * PHW + (ow + 1)) * 32 + lkh * 8;
    }
    const int bkc = wave & 1;

    f32x4 acc[4][2];
    #pragma unroll
    for (int i = 0; i < 4; ++i)
        #pragma unroll
        for (int j = 0; j < 2; ++j)
            acc[i][j] = (f32x4){0.f, 0.f, 0.f, 0.f};

    // staging pieces for tile tn into buf[tn%3]
    auto STAGE_A0 = [&](int tn) {
        const int tap = tn >> 1, cc = (tn & 1) * 2;
        gload16(aw + (size_t)(tap * 4 + cc) * 512,
                &lds[(tn % 3) * BUFH] + (wave * 2 + 0) * 512);
    };
    auto STAGE_A1 = [&](int tn) {
        const int tap = tn >> 1, cc = (tn & 1) * 2 + 1;
        gload16(aw + (size_t)(tap * 4 + cc) * 512,
                &lds[(tn % 3) * BUFH] + (wave * 2 + 1) * 512);
    };
    auto STAGE_B = [&](int tn) {
        const int tap = tn >> 1, cc = (tn & 1) * 2 + bkc;
        const int dr = tap / 3 - 1, dsx = tap % 3 - 1;
        gload16(bsrc + (size_t)cc * (PADTOT_AL * 32) + (dr * PHW + dsx) * 32,
                &lds[(tn % 3) * BUFH] + 16384 + wave * 512);
    };

    // register fragment double-buffer (named, statically indexed — rule #20)
    bf16x8 a0[4], b0[2], a1[4], b1[2];

    auto READ0 = [&](int tn, int ks) {
        const unsigned short* Ab = &lds[(tn % 3) * BUFH];
        #pragma unroll
        for (int mi = 0; mi < 4; ++mi)
            a0[mi] = *reinterpret_cast<const bf16x8*>(
                &Ab[((wr * 4 + mi) * 2 + ks) * 512 + lane * 8]);
        #pragma unroll
        for (int nj = 0; nj < 2; ++nj)
            b0[nj] = *reinterpret_cast<const bf16x8*>(
                &Ab[16384 + ((wc * 2 + nj) * 2 + ks) * 512 + lane * 8]);
    };
    auto READ1 = [&](int tn, int ks) {
        const unsigned short* Ab = &lds[(tn % 3) * BUFH];
        #pragma unroll
        for (int mi = 0; mi < 4; ++mi)
            a1[mi] = *reinterpret_cast<const bf16x8*>(
                &Ab[((wr * 4 + mi) * 2 + ks) * 512 + lane * 8]);
        #pragma unroll
        for (int nj = 0; nj < 2; ++nj)
            b1[nj] = *reinterpret_cast<const bf16x8*>(
                &Ab[16384 + ((wc * 2 + nj) * 2 + ks) * 512 + lane * 8]);
    };

    // prologue: tiles 0 and 1 fully staged (3+3 loads/wave); wait tile-0
    STAGE_A0(0); STAGE_A1(0); STAGE_B(0);
    STAGE_A0(1); STAGE_A1(1); STAGE_B(1);
    asm volatile("s_waitcnt vmcnt(3)" ::: "memory");
    __builtin_amdgcn_s_barrier();
    asm volatile("" ::: "memory");
    READ0(0, 0);                       // 6 ds_read in flight into the loop

    #pragma unroll
    for (int t = 0; t < NTILE; ++t) {
        // phase A: issue next-phase reads + 2/3 of next-next stage, MFMA on G0
        READ1(t, 1);                   // 6 ds_read (buf[t%3])
        if (t + 2 < NTILE) { STAGE_A0(t + 2); STAGE_B(t + 2); }
        asm volatile("s_waitcnt lgkmcnt(6)" ::: "memory");   // G0 done, G1 flying
        __builtin_amdgcn_sched_barrier(0);
        __builtin_amdgcn_s_setprio(1);
        #pragma unroll
        for (int mi = 0; mi < 4; ++mi)
            #pragma unroll
            for (int nj = 0; nj < 2; ++nj)
                acc[mi][nj] = __builtin_amdgcn_mfma_f32_16x16x32_bf16(
                    a0[mi], b0[nj], acc[mi][nj], 0, 0, 0);
        __builtin_amdgcn_s_setprio(0);

        // phase B: finish staging, drain reads, ONE barrier, prefetch-read
        // next tile's first phase, then MFMA on G1
        if (t + 2 < NTILE) STAGE_A1(t + 2);
        asm volatile("s_waitcnt lgkmcnt(0)" ::: "memory");   // all reads of buf[t%3] drained
        __builtin_amdgcn_sched_barrier(0);
        if (t + 1 < NTILE) {
            if (t + 2 < NTILE)
                asm volatile("s_waitcnt vmcnt(3)" ::: "memory");  // t+1 landed; t+2 flying
            else
                asm volatile("s_waitcnt vmcnt(0)" ::: "memory");
            __builtin_amdgcn_s_barrier();
            asm volatile("" ::: "memory");
            READ0(t + 1, 0);           // 6 ds_read (buf[(t+1)%3]), fly over MFMA-B
        }
        __builtin_amdgcn_s_setprio(1);
        #pragma unroll
        for (int mi = 0; mi < 4; ++mi)
            #pragma unroll
            for (int nj = 0; nj < 2; ++nj)
                acc[mi][nj] = __builtin_amdgcn_mfma_f32_16x16x32_bf16(
                    a1[mi], b1[nj], acc[mi][nj], 0, 0, 0);
        __builtin_amdgcn_s_setprio(0);
    }

    // ---- epilogue: D col = lane&15, row = (lane>>4)*4 + reg ----
    #pragma unroll
    for (int mi = 0; mi < 4; ++mi) {
        const int mb = wr * 64 + mi * 16 + lkh * 4;
        const f32x4 bv4 = *reinterpret_cast<const f32x4*>(&bias[mb]);
        #pragma unroll
        for (int nj = 0; nj < 2; ++nj) {
            const int gcol = g0 + wc * 32 + nj * 16;   // 16-aligned: one image
            const int n2 = gcol / SPATIAL;
            const int p2 = gcol - n2 * SPATIAL + la;
            float* op = out + ((size_t)(n2 * K_OUT + mb)) * SPATIAL + p2;
            op[0]                   = acc[mi][nj][0] + bv4[0];
            op[SPATIAL]             = acc[mi][nj][1] + bv4[1];
            op[2 * SPATIAL]         = acc[mi][nj][2] + bv4[2];
            op[3 * (size_t)SPATIAL] = acc[mi][nj][3] + bv4[3];
        }
    }
}

// ---------------- fallback (round-1 path) if ws is too small ----------------
#define LDK 40
__global__ __launch_bounds__(256)
void conv_mfma_fallback(const float* __restrict__ in,
                        const float* __restrict__ wraw,
                        const float* __restrict__ bias,
                        float* __restrict__ out) {
    __shared__ __attribute__((aligned(16))) unsigned short lA[128 * LDK];
    __shared__ __attribute__((aligned(16))) unsigned short lB[128 * LDK];
    const int tid = threadIdx.x;
    const int m0  = blockIdx.y * 128;
    const int g0  = blockIdx.x * 128;
    const int wave = tid >> 6, lane = tid & 63;
    const int wr = wave >> 1, wc = wave & 1;
    const int la = lane & 15, lkh = lane >> 4, lk = lkh * 8;

    f32x4 acc[4][4];
    #pragma unroll
    for (int i = 0; i < 4; ++i)
        #pragma unroll
        for (int j = 0; j < 4; ++j)
            acc[i][j] = (f32x4){0.f, 0.f, 0.f, 0.f};

    const int jj = tid & 127;
    const int kb = (tid >> 7) * 16;
    const int g = g0 + jj;
    const int nimg = g / SPATIAL;
    const int pos  = g % SPATIAL;
    const int oh = pos / HW, ow = pos % HW;

    for (int tap = 0; tap < 9; ++tap) {
        const int dr = tap / 3 - 1, dsx = tap % 3 - 1;
        const int ih = oh + dr, iw = ow + dsx;
        const bool valid = ((unsigned)ih < HW) && ((unsigned)iw < HW);
        const float* src = in + ((nimg * C_IN) * HW + ih) * HW + iw;
        for (int c0 = 0; c0 < C_IN; c0 += 32) {
            #pragma unroll
            for (int i = 0; i < 2; ++i) {
                const int ch = tid * 2 + i;
                const int row = ch >> 2;
                const int kp = (ch & 3) * 8;
                ushort8 v;
                #pragma unroll
                for (int e = 0; e < 8; ++e)
                    v[e] = f2bf(wraw[((m0 + row) * C_IN + c0 + kp + e) * 9 + tap]);
                *reinterpret_cast<ushort8*>(&lA[row * LDK + kp]) = v;
            }
            {
                ushort8 v0, v1;
                #pragma unroll
                for (int i = 0; i < 8; ++i)
                    v0[i] = f2bf(valid ? src[(c0 + kb + i) * SPATIAL] : 0.f);
                #pragma unroll
                for (int i = 0; i < 8; ++i)
                    v1[i] = f2bf(valid ? src[(c0 + kb + 8 + i) * SPATIAL] : 0.f);
                *reinterpret_cast<ushort8*>(&lB[jj * LDK + kb])     = v0;
                *reinterpret_cast<ushort8*>(&lB[jj * LDK + kb + 8]) = v1;
            }
            __syncthreads();
            bf16x8 af[4], bv[4];
            #pragma unroll
            for (int f = 0; f < 4; ++f) {
                af[f] = *reinterpret_cast<const bf16x8*>(&lA[(wr * 64 + f * 16 + la) * LDK + lk]);
                bv[f] = *reinterpret_cast<const bf16x8*>(&lB[(wc * 64 + f * 16 + la) * LDK + lk]);
            }
            #pragma unroll
            for (int fi = 0; fi < 4; ++fi)
                #pragma unroll
                for (int fj = 0; fj < 4; ++fj)
                    acc[fi][fj] = __builtin_amdgcn_mfma_f32_16x16x32_bf16(
                        af[fi], bv[fj], acc[fi][fj], 0, 0, 0);
            __syncthreads();
        }
    }
    const int mbase = m0 + wr * 64;
    const int cbase = g0 + wc * 64;
    #pragma unroll
    for (int fi = 0; fi < 4; ++fi) {
        float bvv[4];
        #pragma unroll
        for (int r = 0; r < 4; ++r)
            bvv[r] = bias[mbase + fi * 16 + lkh * 4 + r];
        #pragma unroll
        for (int fj = 0; fj < 4; ++fj) {
            const int gcol = cbase + fj * 16 + la;
            const int n2 = gcol / SPATIAL;
            const int p2 = gcol % SPATIAL;
            float* op = out + (size_t)(n2 * K_OUT) * SPATIAL + p2;
            #pragma unroll
            for (int r = 0; r < 4; ++r)
                op[(size_t)(mbase + fi * 16 + lkh * 4 + r) * SPATIAL] = acc[fi][fj][r] + bvv[r];
        }
    }
}

extern "C" void kernel_launch(void* const* d_in, const int* in_sizes, int n_in,
                              void* d_out, int out_size, void* d_ws, size_t ws_size,
                              hipStream_t stream) {
    const float* in   = (const float*)d_in[0];
    const float* w    = (const float*)d_in[1];
    const float* bias = (const float*)d_in[2];
    float* out = (float*)d_out;

    // ws layout (halves): pad [4*PADTOT_AL*32] | w3 [294912]
    const size_t pad_halves = 4ull * PADTOT_AL * 32ull;     // 13,779,968
    const size_t need_bytes = (pad_halves + 294912ull) * 2ull;  // ~28.15 MB

    if (ws_size >= need_bytes) {
        unsigned short* pad = (unsigned short*)d_ws;
        unsigned short* w3  = pad + pad_halves;
        prep_all<<<1266 + 32 * HW, 256, 0, stream>>>(w, w3, in, pad);
        conv_tlp<<<GEMM_N / BN, 1024, 0, stream>>>(pad, w3, bias, out);
    } else {
        dim3 grid(GEMM_N / 128, K_OUT / 128);
        conv_mfma_fallback<<<grid, 256, 0, stream>>>(in, w, bias, out);
    }
}